// Round 9
// baseline (227.837 us; speedup 1.0000x reference)
//
#include <hip/hip_runtime.h>
#include <hip/hip_cooperative_groups.h>
#include <cstddef>
#include <cstdint>

namespace cg = cooperative_groups;

// Problem constants (match reference setup_inputs)
#define HH    128
#define WW    128
#define CC    392           // K*K*8 = 49*8
#define NPIX  (HH*WW)       // 16384
#define NROI  2048
#define PSK   7
#define NBIN  49
#define LAMDA 0.1f

// MFMA conv layout constants
#define CPAD      448       // input channels padded to 7*64
#define HPAD      130       // 128 + 1px zero halo each side
#define NPADCO    416       // Bth co rows allocated (13 tiles of 32; conv uses 400)
#define SEGSTRIDE (9*CPAD)  // 4032 elems per co row in Bth
#define BKK       64        // K-chunk per barrier
#define NQ        63        // 9 segs x 7 chunk-iters

// mega-kernel geometry
#define NBLK    1024
#define NTHR    256
#define GSTRIDE (NBLK*NTHR)
#define FTOT    (HPAD*HPAD*(CPAD/8))    // 946400 feature half8-groups
#define WTILES  (9*14*13)               // 1638 weight 32x32 tiles
#define POOLTOT (NROI*NBIN*4)           // 401408 = 1568*256 exactly

typedef _Float16 half8   __attribute__((ext_vector_type(8)));
typedef _Float16 half2v  __attribute__((ext_vector_type(2)));
typedef float    floatx4 __attribute__((ext_vector_type(4)));

// ---------------------------------------------------------------------------
// async global->LDS 16B (dest = wave-uniform base + lane*16)
// ---------------------------------------------------------------------------
__device__ __forceinline__ void async_ld16(const _Float16* g, _Float16* l) {
  __builtin_amdgcn_global_load_lds((const __attribute__((address_space(1))) void*)g,
                                   (__attribute__((address_space(3))) void*)l,
                                   16, 0, 0);
}

// ---------------------------------------------------------------------------
// Prep 1: features fp32 [128,128,392] -> f16 [130,130,448] halo+pad (grid-stride)
// ---------------------------------------------------------------------------
__device__ __forceinline__ void prep_features(const float* __restrict__ F,
                                              _Float16* __restrict__ Fh,
                                              int gtid, int stride) {
  for (int idx = gtid; idx < FTOT; idx += stride) {
    const int p   = idx / (CPAD / 8);
    const int cgi = idx - p * (CPAD / 8);
    const int c   = cgi * 8;
    const int py  = p / HPAD;
    const int px  = p - py * HPAD;
    half8 h;
#pragma unroll
    for (int i = 0; i < 8; ++i) h[i] = (_Float16)0.f;
    if (py >= 1 && py <= HH && px >= 1 && px <= WW && c < CC) {
      const float* src = F + ((size_t)(py - 1) * WW + (px - 1)) * CC + c;
      const float4 v0 = *(const float4*)src;
      const float4 v1 = *(const float4*)(src + 4);
      h[0] = (_Float16)v0.x; h[1] = (_Float16)v0.y;
      h[2] = (_Float16)v0.z; h[3] = (_Float16)v0.w;
      h[4] = (_Float16)v1.x; h[5] = (_Float16)v1.y;
      h[6] = (_Float16)v1.z; h[7] = (_Float16)v1.w;
    }
    *(half8*)(Fh + (size_t)p * CPAD + c) = h;
  }
}

// ---------------------------------------------------------------------------
// Prep 2: weights fp32 [9,392,392] (seg,ci,co) -> f16 Bth[co][seg][ci'] via
// 32x32 LDS tile transpose; co rows 0..415 (392.. zero), ci padded to 448.
// ---------------------------------------------------------------------------
__device__ __forceinline__ void prep_weights(const float* __restrict__ Wt,
                                             _Float16* __restrict__ Bth,
                                             float (*tile)[33],
                                             int bid, int t, int nblocks) {
  for (int tl = bid; tl < WTILES; tl += nblocks) {
    const int seg = tl / (14 * 13);
    const int rem = tl - seg * (14 * 13);
    const int cit = rem / 13;         // ci tile 0..13
    const int cot = rem - cit * 13;   // co tile 0..12
    const int ci0 = cit * 32, co0 = cot * 32;
    __syncthreads();                  // protect tile reuse across iterations
#pragma unroll
    for (int i = 0; i < 4; ++i) {
      const int idx = t + i * 256;
      const int lr = idx >> 5;        // local ci
      const int lc = idx & 31;        // local co (fast -> coalesced read)
      const int ci = ci0 + lr, co = co0 + lc;
      float v = 0.f;
      if (ci < CC && co < CC) v = Wt[((size_t)seg * CC + ci) * CC + co];
      tile[lr][lc] = v;
    }
    __syncthreads();
#pragma unroll
    for (int i = 0; i < 4; ++i) {
      const int idx = t + i * 256;
      const int lr = idx >> 5;        // local co
      const int lc = idx & 31;        // local ci (fast -> coalesced write)
      Bth[(size_t)(co0 + lr) * SEGSTRIDE + seg * CPAD + ci0 + lc] = (_Float16)tile[lc][lr];
    }
  }
}

// ---------------------------------------------------------------------------
// Fat conv tile (flatmm-lite): 128M x 128N, BK=64, 4 waves 2x2, wave 64x64 =
// 4x4 mfma_f32_16x16x32_f16 x2 per barrier. A-fragments loaded DIRECT from
// global (line-coalesced dwordx4, no LDS stage); B staged in LDS with swizzle
// (row r's logical 16B-group g at phys g^(r&7) -> conflict-free ds_read_b128).
// K range [q0,q1). f16 store to OMp.
// ---------------------------------------------------------------------------
__device__ __forceinline__ void conv_fat(const _Float16* __restrict__ Fh,
                                         const _Float16* __restrict__ Bth,
                                         _Float16* __restrict__ OMp,
                                         _Float16* Bs,
                                         int row0, int col0, int q0, int q1, int t) {
  const int L = t & 63;
  const int w = t >> 6;

  const int srow = L >> 3;                 // staging: row within 8-row inst
  const int kofs = ((L & 7) ^ srow) * 8;   // staging: logical halves offset
  const int ya = row0 >> 7;                // image y for this M-tile
  const int nbase = col0 + w * 32 + srow;  // B co row; inst j adds j*8

  const int wm = (w >> 1) * 64;
  const int wn = (w & 1) * 64;
  const int fr = L & 15;
  const int quad = L >> 4;
  const int pg0 = (quad ^ (fr & 7)) * 8;
  const int pg1 = ((4 + quad) ^ (fr & 7)) * 8;

  floatx4 acc[4][4];
#pragma unroll
  for (int i = 0; i < 4; ++i)
#pragma unroll
    for (int j = 0; j < 4; ++j) {
      floatx4 z = {0.f, 0.f, 0.f, 0.f};
      acc[i][j] = z;
    }

  for (int q = q0; q < q1; ++q) {
    const int seg = q / 7;
    const int it  = q - seg * 7;
    const int dy = seg / 3 - 1;
    const int dx = seg - (seg / 3) * 3 - 1;
    const int fy = ya + 1 + dy;
    const int cb = it * BKK;

    // ---- A direct: lane (fr,quad) reads 16B of pixel x = wm+mt*16+fr ----
    const _Float16* gA = Fh + ((size_t)fy * HPAD + (1 + dx) + wm + fr) * CPAD
                            + quad * 8 + cb;
    half8 a0[4], a1[4];
#pragma unroll
    for (int mt = 0; mt < 4; ++mt) {
      a0[mt] = *(const half8*)(gA + (size_t)mt * 16 * CPAD);
      a1[mt] = *(const half8*)(gA + (size_t)mt * 16 * CPAD + 32);
    }

    // ---- B stage to LDS (swizzled) ----
    const _Float16* gB = Bth + (size_t)nbase * SEGSTRIDE + seg * CPAD + kofs + cb;
#pragma unroll
    for (int j = 0; j < 4; ++j)
      async_ld16(gB + (size_t)(j * 8) * SEGSTRIDE, &Bs[(w * 32 + j * 8) * BKK]);
    __syncthreads();   // drains vmcnt -> B tile ready (and A regs ready)

    half8 b0[4], b1[4];
#pragma unroll
    for (int nt = 0; nt < 4; ++nt) {
      const int rb = (wn + nt * 16 + fr) * BKK;
      b0[nt] = *(const half8*)(&Bs[rb + pg0]);
      b1[nt] = *(const half8*)(&Bs[rb + pg1]);
    }
#pragma unroll
    for (int mt = 0; mt < 4; ++mt)
#pragma unroll
      for (int nt = 0; nt < 4; ++nt)
        acc[mt][nt] = __builtin_amdgcn_mfma_f32_16x16x32_f16(a0[mt], b0[nt], acc[mt][nt], 0, 0, 0);
#pragma unroll
    for (int mt = 0; mt < 4; ++mt)
#pragma unroll
      for (int nt = 0; nt < 4; ++nt)
        acc[mt][nt] = __builtin_amdgcn_mfma_f32_16x16x32_f16(a1[mt], b1[nt], acc[mt][nt], 0, 0, 0);
    __syncthreads();   // protect Bs before next chunk's staging
  }

  // epilogue: C/D mapping col=lane&15, row=(lane>>4)*4+reg; f16 partial store
#pragma unroll
  for (int mt = 0; mt < 4; ++mt) {
    const int rbase = row0 + wm + mt * 16 + quad * 4;
#pragma unroll
    for (int nt = 0; nt < 4; ++nt) {
      const int col = col0 + wn + nt * 16 + fr;
      if (col < CC) {
#pragma unroll
        for (int r = 0; r < 4; ++r)
          OMp[(size_t)(rbase + r) * CC + col] = (_Float16)acc[mt][nt][r];
      }
    }
  }
}

// ---------------------------------------------------------------------------
// Thin conv tile (flatmm-lite): 128M x 16N (cols 384..399, real 384..391).
// 4 waves stacked in M (wave 32M x 16N, acc 2x1). A direct from global;
// waves 0-1 stage the 16 B-rows (1 inst each).
// ---------------------------------------------------------------------------
__device__ __forceinline__ void conv_thin(const _Float16* __restrict__ Fh,
                                          const _Float16* __restrict__ Bth,
                                          _Float16* __restrict__ OMp,
                                          _Float16* Bs,
                                          int row0, int q0, int q1, int t) {
  const int L = t & 63;
  const int w = t >> 6;

  const int srow = L >> 3;
  const int kofs = ((L & 7) ^ srow) * 8;
  const int ya = row0 >> 7;
  const int nbase = 384 + w * 8 + srow;    // valid when w < 2

  const int wm = w * 32;
  const int fr = L & 15;
  const int quad = L >> 4;
  const int pg0 = (quad ^ (fr & 7)) * 8;
  const int pg1 = ((4 + quad) ^ (fr & 7)) * 8;

  floatx4 acc[2];
#pragma unroll
  for (int i = 0; i < 2; ++i) {
    floatx4 z = {0.f, 0.f, 0.f, 0.f};
    acc[i] = z;
  }

  for (int q = q0; q < q1; ++q) {
    const int seg = q / 7;
    const int it  = q - seg * 7;
    const int dy = seg / 3 - 1;
    const int dx = seg - (seg / 3) * 3 - 1;
    const int fy = ya + 1 + dy;
    const int cb = it * BKK;

    const _Float16* gA = Fh + ((size_t)fy * HPAD + (1 + dx) + wm + fr) * CPAD
                            + quad * 8 + cb;
    half8 a0[2], a1[2];
#pragma unroll
    for (int mt = 0; mt < 2; ++mt) {
      a0[mt] = *(const half8*)(gA + (size_t)mt * 16 * CPAD);
      a1[mt] = *(const half8*)(gA + (size_t)mt * 16 * CPAD + 32);
    }

    if (w < 2) {
      const _Float16* gB = Bth + (size_t)nbase * SEGSTRIDE + seg * CPAD + kofs + cb;
      async_ld16(gB, &Bs[(w * 8) * BKK]);
    }
    __syncthreads();

    const half8 b0 = *(const half8*)(&Bs[fr * BKK + pg0]);
    const half8 b1 = *(const half8*)(&Bs[fr * BKK + pg1]);
#pragma unroll
    for (int mt = 0; mt < 2; ++mt)
      acc[mt] = __builtin_amdgcn_mfma_f32_16x16x32_f16(a0[mt], b0, acc[mt], 0, 0, 0);
#pragma unroll
    for (int mt = 0; mt < 2; ++mt)
      acc[mt] = __builtin_amdgcn_mfma_f32_16x16x32_f16(a1[mt], b1, acc[mt], 0, 0, 0);
    __syncthreads();
  }

#pragma unroll
  for (int mt = 0; mt < 2; ++mt) {
    const int rbase = row0 + wm + mt * 16 + quad * 4;
    const int col = 384 + fr;
    if (col < CC) {
#pragma unroll
      for (int r = 0; r < 4; ++r)
        OMp[(size_t)(rbase + r) * CC + col] = (_Float16)acc[mt][r];
    }
  }
}

// ---------------------------------------------------------------------------
// Conv block decode: bid in [0,1024). x = bid&127 (M-block), rest = bid>>7:
// rest 0..5 -> fat col {0,1,2}, kz = rest/3. rest 6,7 -> thin, kz = rest-6.
// ---------------------------------------------------------------------------
__device__ __forceinline__ void conv_dispatch(const _Float16* Fh, const _Float16* Bth,
                                              _Float16* OMa, _Float16* OMb,
                                              _Float16* Bs, int bid, int t) {
  const int x = bid & 127;
  const int rest = bid >> 7;
  const int kz = (rest < 6) ? (rest / 3) : (rest - 6);
  _Float16* OMp = kz ? OMb : OMa;
  const int q0 = kz * 32;
  const int q1 = kz ? NQ : 32;
  if (rest < 6)
    conv_fat(Fh, Bth, OMp, Bs, x * 128, (rest % 3) * 128, q0, q1, t);
  else
    conv_thin(Fh, Bth, OMp, Bs, x * 128, q0, q1, t);
}

// ---------------------------------------------------------------------------
// Pool: one item per (roi, bin, group); the 4 lanes of a quad share (roi,bin)
// and double as the 4 bilinear corners for stage 1: lane q loads its corner's
// half8 from BOTH split-K maps (2x16B), scales by its corner weight, and 2
// butterfly shuffles give every lane the full o[8]. Stage 2 per lane (group q).
// ---------------------------------------------------------------------------
__device__ __forceinline__ void bilin_setup(float y, float x,
                                            int& iy0, int& iy1, int& ix0, int& ix1,
                                            float& w00, float& w01, float& w10, float& w11) {
  const float y0f = floorf(y), x0f = floorf(x);
  const float wy = y - y0f, wx = x - x0f;   // unclamped, matches reference
  const int a = (int)y0f, b = (int)x0f;
  iy0 = min(max(a, 0), HH - 1);
  iy1 = min(max(a + 1, 0), HH - 1);
  ix0 = min(max(b, 0), WW - 1);
  ix1 = min(max(b + 1, 0), WW - 1);
  w00 = (1.f - wy) * (1.f - wx);
  w01 = (1.f - wy) * wx;
  w10 = wy * (1.f - wx);
  w11 = wy * wx;
}

__device__ __forceinline__ void pool_item(const _Float16* __restrict__ Fh,
                                          const float* __restrict__ R,
                                          const _Float16* __restrict__ OMa,
                                          const _Float16* __restrict__ OMb,
                                          float* __restrict__ out, int tid) {
  const int q  = tid & 3;          // == group g AND stage-1 corner id
  const int nb = tid >> 2;
  const int n  = nb / NBIN;
  const int b  = nb - n * NBIN;
  const int bi = b / PSK;
  const int bj = b - bi * PSK;

  const float rx1 = R[n * 5 + 1], ry1 = R[n * 5 + 2];
  const float rx2 = R[n * 5 + 3], ry2 = R[n * 5 + 4];
  const float x1 = rx1 * (1.f / 16.f);
  const float y1 = ry1 * (1.f / 16.f);
  const float x2 = (rx2 + 1.f) * (1.f / 16.f);
  const float y2 = (ry2 + 1.f) * (1.f / 16.f);
  const float bw = (x2 - x1) * (1.f / 7.f);
  const float bh = (y2 - y1) * (1.f / 7.f);
  const float cx = x1 + ((float)bj + 0.5f) * bw;
  const float cy = y1 + ((float)bi + 0.5f) * bh;
  const float sxs = (rx2 - rx1 + 1.f) * (LAMDA / 16.f);
  const float sys = (ry2 - ry1 + 1.f) * (LAMDA / 16.f);

  // ---- stage 1: lane q = corner q; half8 from both maps, shuffle-reduce ----
  int iy0, iy1, ix0, ix1;
  float w00, w01, w10, w11;
  bilin_setup(cy, cx, iy0, iy1, ix0, ix1, w00, w01, w10, w11);

  const int cyi = (q >> 1) ? iy1 : iy0;
  const int cxi = (q & 1) ? ix1 : ix0;
  const float wq = (q == 0) ? w00 : (q == 1) ? w01 : (q == 2) ? w10 : w11;

  const size_t base = (size_t)(cyi * WW + cxi) * CC + (size_t)b * 8;
  const half8 ha = *(const half8*)(OMa + base);
  const half8 hb = *(const half8*)(OMb + base);

  float o8[8];
#pragma unroll
  for (int i = 0; i < 8; ++i)
    o8[i] = wq * ((float)ha[i] + (float)hb[i]);
#pragma unroll
  for (int i = 0; i < 8; ++i) o8[i] += __shfl_xor(o8[i], 1);
#pragma unroll
  for (int i = 0; i < 8; ++i) o8[i] += __shfl_xor(o8[i], 2);

  const float sx = cx + o8[2 * q] * sxs;
  const float sy = cy + o8[2 * q + 1] * sys;

  // ---- stage 2: deformable sample of f16 features (halo layout), group q ----
  int jy0, jy1, jx0, jx1;
  float u00, u01, u10, u11;
  bilin_setup(sy, sx, jy0, jy1, jx0, jx1, u00, u01, u10, u11);

  const size_t c0 = (size_t)b * 8 + 2 * q;
  const half2v q00 = *(const half2v*)(Fh + ((size_t)(jy0 + 1) * HPAD + (jx0 + 1)) * CPAD + c0);
  const half2v q01 = *(const half2v*)(Fh + ((size_t)(jy0 + 1) * HPAD + (jx1 + 1)) * CPAD + c0);
  const half2v q10 = *(const half2v*)(Fh + ((size_t)(jy1 + 1) * HPAD + (jx0 + 1)) * CPAD + c0);
  const half2v q11 = *(const half2v*)(Fh + ((size_t)(jy1 + 1) * HPAD + (jx1 + 1)) * CPAD + c0);

  const float v0 = u00 * (float)q00[0] + u01 * (float)q01[0]
                 + u10 * (float)q10[0] + u11 * (float)q11[0];
  const float v1 = u00 * (float)q00[1] + u01 * (float)q01[1]
                 + u10 * (float)q10[1] + u11 * (float)q11[1];

  out[((size_t)n * 8 + 2 * q + 0) * NBIN + b] = v0;
  out[((size_t)n * 8 + 2 * q + 1) * NBIN + b] = v1;
}

// ---------------------------------------------------------------------------
// Cooperative kernel: prep -> grid.sync -> split-K conv (all 1024 blocks).
// LDS now 16 KB (B tile only; prep transpose tile aliases it).
// ---------------------------------------------------------------------------
__global__ __launch_bounds__(NTHR, 4)
void mega_kernel(const float* __restrict__ F, const float* __restrict__ Wt,
                 _Float16* __restrict__ OMa, _Float16* __restrict__ OMb,
                 _Float16* __restrict__ Fh, _Float16* __restrict__ Bth) {
  __shared__ __align__(16) _Float16 smem[128 * BKK];  // 16 KB
  const int bid = blockIdx.x;
  const int t = threadIdx.x;
  cg::grid_group grid = cg::this_grid();

  prep_features(F, Fh, bid * NTHR + t, GSTRIDE);
  prep_weights(Wt, Bth, (float(*)[33])smem, bid, t, NBLK);

  __threadfence();
  grid.sync();

  conv_dispatch(Fh, Bth, OMa, OMb, smem, bid, t);
}

__global__ __launch_bounds__(256)
void pool_kernel(const _Float16* __restrict__ Fh, const float* __restrict__ R,
                 const _Float16* __restrict__ OMa, const _Float16* __restrict__ OMb,
                 float* __restrict__ out) {
  pool_item(Fh, R, OMa, OMb, out, blockIdx.x * 256 + threadIdx.x);
}

// ---------------------------------------------------------------------------
// Non-coop fallback (same device code, separate launches)
// ---------------------------------------------------------------------------
__global__ __launch_bounds__(256)
void prep_kernel_sa(const float* __restrict__ F, const float* __restrict__ Wt,
                    _Float16* __restrict__ Fh, _Float16* __restrict__ Bth) {
  __shared__ float tile[32][33];
  prep_features(F, Fh, blockIdx.x * 256 + threadIdx.x, gridDim.x * 256);
  prep_weights(Wt, Bth, tile, blockIdx.x, threadIdx.x, gridDim.x);
}

__global__ __launch_bounds__(256, 4)
void conv_kernel_sa(const _Float16* __restrict__ Fh, const _Float16* __restrict__ Bth,
                    _Float16* __restrict__ OMa, _Float16* __restrict__ OMb) {
  __shared__ __align__(16) _Float16 smem[128 * BKK];
  conv_dispatch(Fh, Bth, OMa, OMb, smem, blockIdx.x, threadIdx.x);
}

extern "C" void kernel_launch(void* const* d_in, const int* in_sizes, int n_in,
                              void* d_out, int out_size, void* d_ws, size_t ws_size,
                              hipStream_t stream) {
  const float* F  = (const float*)d_in[0];   // features [1,128,128,392] fp32
  const float* R  = (const float*)d_in[1];   // rois [2048,5] fp32
  const float* Wt = (const float*)d_in[2];   // conv_w [3,3,392,392] fp32
  float* out = (float*)d_out;                // [2048,8,7,7] fp32

  const size_t omBytes  = (size_t)NPIX * CC * sizeof(_Float16);            // 12.85 MB
  const size_t fhBytes  = (size_t)HPAD * HPAD * CPAD * sizeof(_Float16);   // 15.14 MB
  // Bth: 416 * 4032 * 2B = 3.35 MB; total ~44.2 MB

  _Float16* OMa = (_Float16*)d_ws;
  _Float16* OMb = OMa + (size_t)NPIX * CC;
  _Float16* Fh  = (_Float16*)((char*)d_ws + 2 * omBytes);
  _Float16* Bth = (_Float16*)((char*)d_ws + 2 * omBytes + fhBytes);

  int maxBlk = 0;
  hipError_t qerr = hipOccupancyMaxActiveBlocksPerMultiprocessor(&maxBlk, mega_kernel, NTHR, 0);
  bool coopOk = (qerr == hipSuccess && maxBlk >= 4);

  if (coopOk) {
    void* args[] = {(void*)&F, (void*)&Wt, (void*)&OMa, (void*)&OMb,
                    (void*)&Fh, (void*)&Bth};
    hipError_t err = hipLaunchCooperativeKernel((const void*)mega_kernel,
                                                dim3(NBLK), dim3(NTHR),
                                                args, 0, stream);
    if (err != hipSuccess) {
      (void)hipGetLastError();
      coopOk = false;
    }
  }
  if (!coopOk) {
    prep_kernel_sa<<<2048, 256, 0, stream>>>(F, Wt, Fh, Bth);
    conv_kernel_sa<<<NBLK, 256, 0, stream>>>(Fh, Bth, OMa, OMb);
  }

  pool_kernel<<<POOLTOT / 256, 256, 0, stream>>>(Fh, R, OMa, OMb, out);
}

// Round 10
// 157.462 us; speedup vs baseline: 1.4469x; 1.4469x over previous
//
#include <hip/hip_runtime.h>
#include <hip/hip_cooperative_groups.h>
#include <cstddef>
#include <cstdint>

namespace cg = cooperative_groups;

// Problem constants (match reference setup_inputs)
#define HH    128
#define WW    128
#define CC    392           // K*K*8 = 49*8
#define NPIX  (HH*WW)       // 16384
#define NROI  2048
#define PSK   7
#define NBIN  49
#define LAMDA 0.1f

// MFMA conv layout constants
#define CPAD      448       // input channels padded to 7*64
#define HPAD      130       // 128 + 1px zero halo each side
#define NPADCO    416       // Bth co rows allocated (13 tiles of 32; conv uses 400)
#define SEGSTRIDE (9*CPAD)  // 4032 elems per co row in Bth
#define BKK       64        // K-chunk per barrier
#define NQ        63        // 9 segs x 7 chunk-iters

// mega-kernel geometry
#define NBLK    1024
#define NTHR    256
#define GSTRIDE (NBLK*NTHR)
#define FTOT    (HPAD*HPAD*(CPAD/8))    // 946400 feature half8-groups
#define WTILES  (9*14*13)               // 1638 weight 32x32 tiles
#define POOL8   (NROI*NBIN*8)           // 802816 = 3136*256 exactly

typedef _Float16 half8   __attribute__((ext_vector_type(8)));
typedef _Float16 half2v  __attribute__((ext_vector_type(2)));
typedef float    floatx4 __attribute__((ext_vector_type(4)));

// ---------------------------------------------------------------------------
// async global->LDS 16B (dest = wave-uniform base + lane*16)
// ---------------------------------------------------------------------------
__device__ __forceinline__ void async_ld16(const _Float16* g, _Float16* l) {
  __builtin_amdgcn_global_load_lds((const __attribute__((address_space(1))) void*)g,
                                   (__attribute__((address_space(3))) void*)l,
                                   16, 0, 0);
}

// ---------------------------------------------------------------------------
// Prep 1: features fp32 [128,128,392] -> f16 [130,130,448] halo+pad (grid-stride)
// ---------------------------------------------------------------------------
__device__ __forceinline__ void prep_features(const float* __restrict__ F,
                                              _Float16* __restrict__ Fh,
                                              int gtid, int stride) {
  for (int idx = gtid; idx < FTOT; idx += stride) {
    const int p   = idx / (CPAD / 8);
    const int cgi = idx - p * (CPAD / 8);
    const int c   = cgi * 8;
    const int py  = p / HPAD;
    const int px  = p - py * HPAD;
    half8 h;
#pragma unroll
    for (int i = 0; i < 8; ++i) h[i] = (_Float16)0.f;
    if (py >= 1 && py <= HH && px >= 1 && px <= WW && c < CC) {
      const float* src = F + ((size_t)(py - 1) * WW + (px - 1)) * CC + c;
      const float4 v0 = *(const float4*)src;
      const float4 v1 = *(const float4*)(src + 4);
      h[0] = (_Float16)v0.x; h[1] = (_Float16)v0.y;
      h[2] = (_Float16)v0.z; h[3] = (_Float16)v0.w;
      h[4] = (_Float16)v1.x; h[5] = (_Float16)v1.y;
      h[6] = (_Float16)v1.z; h[7] = (_Float16)v1.w;
    }
    *(half8*)(Fh + (size_t)p * CPAD + c) = h;
  }
}

// ---------------------------------------------------------------------------
// Prep 2: weights fp32 [9,392,392] (seg,ci,co) -> f16 Bth[co][seg][ci'] via
// 32x32 LDS tile transpose; co rows 0..415 (392.. zero), ci padded to 448.
// ---------------------------------------------------------------------------
__device__ __forceinline__ void prep_weights(const float* __restrict__ Wt,
                                             _Float16* __restrict__ Bth,
                                             float (*tile)[33],
                                             int bid, int t, int nblocks) {
  for (int tl = bid; tl < WTILES; tl += nblocks) {
    const int seg = tl / (14 * 13);
    const int rem = tl - seg * (14 * 13);
    const int cit = rem / 13;         // ci tile 0..13
    const int cot = rem - cit * 13;   // co tile 0..12
    const int ci0 = cit * 32, co0 = cot * 32;
    __syncthreads();                  // protect tile reuse across iterations
#pragma unroll
    for (int i = 0; i < 4; ++i) {
      const int idx = t + i * 256;
      const int lr = idx >> 5;        // local ci
      const int lc = idx & 31;        // local co (fast -> coalesced read)
      const int ci = ci0 + lr, co = co0 + lc;
      float v = 0.f;
      if (ci < CC && co < CC) v = Wt[((size_t)seg * CC + ci) * CC + co];
      tile[lr][lc] = v;
    }
    __syncthreads();
#pragma unroll
    for (int i = 0; i < 4; ++i) {
      const int idx = t + i * 256;
      const int lr = idx >> 5;        // local co
      const int lc = idx & 31;        // local ci (fast -> coalesced write)
      Bth[(size_t)(co0 + lr) * SEGSTRIDE + seg * CPAD + ci0 + lc] = (_Float16)tile[lc][lr];
    }
  }
}

// ---------------------------------------------------------------------------
// Fat conv tile (R8-verified): 128M x 128N, BK=64, 4 waves 2x2, wave 64x64 =
// 4x4 mfma_f32_16x16x32_f16 x2 per barrier. A+B staged via global_load_lds.
// LDS swizzle: row r's logical 16B-group g at phys g^(r&7) -> conflict-free.
// ---------------------------------------------------------------------------
__device__ __forceinline__ void conv_fat(const _Float16* __restrict__ Fh,
                                         const _Float16* __restrict__ Bth,
                                         _Float16* __restrict__ OMp,
                                         _Float16* As, _Float16* Bs,
                                         int row0, int col0, int q0, int q1, int t) {
  const int L = t & 63;
  const int w = t >> 6;

  const int srow = L >> 3;                 // 0..7 row within 8-row staging inst
  const int kofs = ((L & 7) ^ srow) * 8;   // logical halves offset this lane fetches
  const int ya = row0 >> 7;                // image y for this M-tile
  const int nbase = col0 + w * 32 + srow;  // B co row; inst j adds j*8

  const int wm = (w >> 1) * 64;
  const int wn = (w & 1) * 64;
  const int fr = L & 15;
  const int quad = L >> 4;
  const int pg0 = (quad ^ (fr & 7)) * 8;
  const int pg1 = ((4 + quad) ^ (fr & 7)) * 8;

  floatx4 acc[4][4];
#pragma unroll
  for (int i = 0; i < 4; ++i)
#pragma unroll
    for (int j = 0; j < 4; ++j) {
      floatx4 z = {0.f, 0.f, 0.f, 0.f};
      acc[i][j] = z;
    }

  for (int q = q0; q < q1; ++q) {
    const int seg = q / 7;
    const int it  = q - seg * 7;
    const int dy = seg / 3 - 1;
    const int dx = seg - (seg / 3) * 3 - 1;
    const int fy = ya + 1 + dy;
    const int cb = it * BKK;
    const _Float16* gArow = Fh + ((size_t)fy * HPAD + (1 + dx)) * CPAD + kofs + cb;
    const _Float16* gB = Bth + (size_t)nbase * SEGSTRIDE + seg * CPAD + kofs + cb;

#pragma unroll
    for (int j = 0; j < 4; ++j) {
      const int xr = w * 32 + j * 8 + srow;  // tile row == pixel x
      async_ld16(gArow + (size_t)xr * CPAD, &As[(w * 32 + j * 8) * BKK]);
    }
#pragma unroll
    for (int j = 0; j < 4; ++j)
      async_ld16(gB + (size_t)(j * 8) * SEGSTRIDE, &Bs[(w * 32 + j * 8) * BKK]);
    __syncthreads();   // drains vmcnt -> LDS tiles ready

    half8 a0[4], a1[4], b0[4], b1[4];
#pragma unroll
    for (int mt = 0; mt < 4; ++mt) {
      const int rb = (wm + mt * 16 + fr) * BKK;
      a0[mt] = *(const half8*)(&As[rb + pg0]);
      a1[mt] = *(const half8*)(&As[rb + pg1]);
    }
#pragma unroll
    for (int nt = 0; nt < 4; ++nt) {
      const int rb = (wn + nt * 16 + fr) * BKK;
      b0[nt] = *(const half8*)(&Bs[rb + pg0]);
      b1[nt] = *(const half8*)(&Bs[rb + pg1]);
    }
#pragma unroll
    for (int mt = 0; mt < 4; ++mt)
#pragma unroll
      for (int nt = 0; nt < 4; ++nt)
        acc[mt][nt] = __builtin_amdgcn_mfma_f32_16x16x32_f16(a0[mt], b0[nt], acc[mt][nt], 0, 0, 0);
#pragma unroll
    for (int mt = 0; mt < 4; ++mt)
#pragma unroll
      for (int nt = 0; nt < 4; ++nt)
        acc[mt][nt] = __builtin_amdgcn_mfma_f32_16x16x32_f16(a1[mt], b1[nt], acc[mt][nt], 0, 0, 0);
    __syncthreads();   // protect LDS before next chunk's staging
  }

  // epilogue: C/D mapping col=lane&15, row=(lane>>4)*4+reg; f16 partial store
#pragma unroll
  for (int mt = 0; mt < 4; ++mt) {
    const int rbase = row0 + wm + mt * 16 + quad * 4;
#pragma unroll
    for (int nt = 0; nt < 4; ++nt) {
      const int col = col0 + wn + nt * 16 + fr;
      if (col < CC) {
#pragma unroll
        for (int r = 0; r < 4; ++r)
          OMp[(size_t)(rbase + r) * CC + col] = (_Float16)acc[mt][nt][r];
      }
    }
  }
}

// ---------------------------------------------------------------------------
// Thin conv tile (R8-verified): 128M x 16N (cols 384..399, real 384..391).
// 4 waves stacked in M (wave 32M x 16N, acc 2x1). Waves 0-1 stage B rows.
// ---------------------------------------------------------------------------
__device__ __forceinline__ void conv_thin(const _Float16* __restrict__ Fh,
                                          const _Float16* __restrict__ Bth,
                                          _Float16* __restrict__ OMp,
                                          _Float16* As, _Float16* Bs,
                                          int row0, int q0, int q1, int t) {
  const int L = t & 63;
  const int w = t >> 6;

  const int srow = L >> 3;
  const int kofs = ((L & 7) ^ srow) * 8;
  const int ya = row0 >> 7;
  const int nbase = 384 + w * 8 + srow;    // valid when w < 2

  const int wm = w * 32;
  const int fr = L & 15;
  const int quad = L >> 4;
  const int pg0 = (quad ^ (fr & 7)) * 8;
  const int pg1 = ((4 + quad) ^ (fr & 7)) * 8;

  floatx4 acc[2];
#pragma unroll
  for (int i = 0; i < 2; ++i) {
    floatx4 z = {0.f, 0.f, 0.f, 0.f};
    acc[i] = z;
  }

  for (int q = q0; q < q1; ++q) {
    const int seg = q / 7;
    const int it  = q - seg * 7;
    const int dy = seg / 3 - 1;
    const int dx = seg - (seg / 3) * 3 - 1;
    const int fy = ya + 1 + dy;
    const int cb = it * BKK;
    const _Float16* gArow = Fh + ((size_t)fy * HPAD + (1 + dx)) * CPAD + kofs + cb;

#pragma unroll
    for (int j = 0; j < 4; ++j) {
      const int xr = w * 32 + j * 8 + srow;
      async_ld16(gArow + (size_t)xr * CPAD, &As[(w * 32 + j * 8) * BKK]);
    }
    if (w < 2) {
      const _Float16* gB = Bth + (size_t)nbase * SEGSTRIDE + seg * CPAD + kofs + cb;
      async_ld16(gB, &Bs[(w * 8) * BKK]);
    }
    __syncthreads();

    half8 a0[2], a1[2];
#pragma unroll
    for (int mt = 0; mt < 2; ++mt) {
      const int rb = (wm + mt * 16 + fr) * BKK;
      a0[mt] = *(const half8*)(&As[rb + pg0]);
      a1[mt] = *(const half8*)(&As[rb + pg1]);
    }
    const half8 b0 = *(const half8*)(&Bs[fr * BKK + pg0]);
    const half8 b1 = *(const half8*)(&Bs[fr * BKK + pg1]);
#pragma unroll
    for (int mt = 0; mt < 2; ++mt)
      acc[mt] = __builtin_amdgcn_mfma_f32_16x16x32_f16(a0[mt], b0, acc[mt], 0, 0, 0);
#pragma unroll
    for (int mt = 0; mt < 2; ++mt)
      acc[mt] = __builtin_amdgcn_mfma_f32_16x16x32_f16(a1[mt], b1, acc[mt], 0, 0, 0);
    __syncthreads();
  }

#pragma unroll
  for (int mt = 0; mt < 2; ++mt) {
    const int rbase = row0 + wm + mt * 16 + quad * 4;
    const int col = 384 + fr;
    if (col < CC) {
#pragma unroll
      for (int r = 0; r < 4; ++r)
        OMp[(size_t)(rbase + r) * CC + col] = (_Float16)acc[mt][r];
    }
  }
}

// ---------------------------------------------------------------------------
// Conv block decode: bid in [0,1024). x = bid&127 (M-block), rest = bid>>7:
// rest 0..5 -> fat col {0,1,2}, kz = rest/3. rest 6,7 -> thin, kz = rest-6.
// ---------------------------------------------------------------------------
__device__ __forceinline__ void conv_dispatch(const _Float16* Fh, const _Float16* Bth,
                                              _Float16* OMa, _Float16* OMb,
                                              _Float16* As, _Float16* Bs,
                                              int bid, int t) {
  const int x = bid & 127;
  const int rest = bid >> 7;
  const int kz = (rest < 6) ? (rest / 3) : (rest - 6);
  _Float16* OMp = kz ? OMb : OMa;
  const int q0 = kz * 32;
  const int q1 = kz ? NQ : 32;
  if (rest < 6)
    conv_fat(Fh, Bth, OMp, As, Bs, x * 128, (rest % 3) * 128, q0, q1, t);
  else
    conv_thin(Fh, Bth, OMp, As, Bs, x * 128, q0, q1, t);
}

// ---------------------------------------------------------------------------
// Pool (8 lanes per (roi,bin)): lane j in 0..7.
// Stage 1: corner c=j&3, map m=j>>2 -> ONE half8 load each; butterfly xor
// 1,2 (sum corners within map) then xor 4 (add other map) -> full o[8].
// Stage 2: group g=j&3, y-half h=j>>2 -> TWO half2 loads each (x0,x1 at its
// y-row); xor 4 combines halves. Lane j<4 writes ch 2g, j>=4 writes ch 2g+1.
// Dependent scattered loads per lane: 3 (was 6).
// ---------------------------------------------------------------------------
__device__ __forceinline__ void bilin_setup(float y, float x,
                                            int& iy0, int& iy1, int& ix0, int& ix1,
                                            float& w00, float& w01, float& w10, float& w11) {
  const float y0f = floorf(y), x0f = floorf(x);
  const float wy = y - y0f, wx = x - x0f;   // unclamped, matches reference
  const int a = (int)y0f, b = (int)x0f;
  iy0 = min(max(a, 0), HH - 1);
  iy1 = min(max(a + 1, 0), HH - 1);
  ix0 = min(max(b, 0), WW - 1);
  ix1 = min(max(b + 1, 0), WW - 1);
  w00 = (1.f - wy) * (1.f - wx);
  w01 = (1.f - wy) * wx;
  w10 = wy * (1.f - wx);
  w11 = wy * wx;
}

__device__ __forceinline__ void pool_item8(const _Float16* __restrict__ Fh,
                                           const float* __restrict__ R,
                                           const _Float16* __restrict__ OMa,
                                           const _Float16* __restrict__ OMb,
                                           float* __restrict__ out, int tid) {
  const int j  = tid & 7;          // lane role within (roi,bin)
  const int nb = tid >> 3;
  const int n  = nb / NBIN;
  const int b  = nb - n * NBIN;
  const int bi = b / PSK;
  const int bj = b - bi * PSK;

  const float rx1 = R[n * 5 + 1], ry1 = R[n * 5 + 2];
  const float rx2 = R[n * 5 + 3], ry2 = R[n * 5 + 4];
  const float x1 = rx1 * (1.f / 16.f);
  const float y1 = ry1 * (1.f / 16.f);
  const float x2 = (rx2 + 1.f) * (1.f / 16.f);
  const float y2 = (ry2 + 1.f) * (1.f / 16.f);
  const float bw = (x2 - x1) * (1.f / 7.f);
  const float bh = (y2 - y1) * (1.f / 7.f);
  const float cx = x1 + ((float)bj + 0.5f) * bw;
  const float cy = y1 + ((float)bi + 0.5f) * bh;
  const float sxs = (rx2 - rx1 + 1.f) * (LAMDA / 16.f);
  const float sys = (ry2 - ry1 + 1.f) * (LAMDA / 16.f);

  // ---- stage 1: lane = (corner j&3, map j>>2); one half8 load ----
  int iy0, iy1, ix0, ix1;
  float w00, w01, w10, w11;
  bilin_setup(cy, cx, iy0, iy1, ix0, ix1, w00, w01, w10, w11);

  const int c = j & 3;
  const int cyi = (c >> 1) ? iy1 : iy0;
  const int cxi = (c & 1) ? ix1 : ix0;
  const float wq = (c == 0) ? w00 : (c == 1) ? w01 : (c == 2) ? w10 : w11;

  const _Float16* OMp = (j >> 2) ? OMb : OMa;
  const size_t base = (size_t)(cyi * WW + cxi) * CC + (size_t)b * 8;
  const half8 hv = *(const half8*)(OMp + base);

  float o8[8];
#pragma unroll
  for (int i = 0; i < 8; ++i) o8[i] = wq * (float)hv[i];
#pragma unroll
  for (int i = 0; i < 8; ++i) o8[i] += __shfl_xor(o8[i], 1);
#pragma unroll
  for (int i = 0; i < 8; ++i) o8[i] += __shfl_xor(o8[i], 2);
#pragma unroll
  for (int i = 0; i < 8; ++i) o8[i] += __shfl_xor(o8[i], 4);

  const int g = j & 3;
  const float sx = cx + o8[2 * g] * sxs;
  const float sy = cy + o8[2 * g + 1] * sys;

  // ---- stage 2: lane = (group g, y-half j>>2); two half2 loads ----
  int jy0, jy1, jx0, jx1;
  float u00, u01, u10, u11;
  bilin_setup(sy, sx, jy0, jy1, jx0, jx1, u00, u01, u10, u11);

  const int  yh = j >> 2;
  const int  jy = yh ? jy1 : jy0;
  const float ua = yh ? u10 : u00;   // weight at (jy, jx0)
  const float ub = yh ? u11 : u01;   // weight at (jy, jx1)

  const size_t c0 = (size_t)b * 8 + 2 * g;
  const half2v qa = *(const half2v*)(Fh + ((size_t)(jy + 1) * HPAD + (jx0 + 1)) * CPAD + c0);
  const half2v qb = *(const half2v*)(Fh + ((size_t)(jy + 1) * HPAD + (jx1 + 1)) * CPAD + c0);

  float v0 = ua * (float)qa[0] + ub * (float)qb[0];
  float v1 = ua * (float)qa[1] + ub * (float)qb[1];
  v0 += __shfl_xor(v0, 4);
  v1 += __shfl_xor(v1, 4);

  // lane j<4 writes channel 2g, lane j>=4 writes channel 2g+1 (one store each)
  const float vout = yh ? v1 : v0;
  out[((size_t)n * 8 + 2 * g + yh) * NBIN + b] = vout;
}

// ---------------------------------------------------------------------------
// Cooperative kernel: prep -> grid.sync -> split-K conv (all 1024 blocks).
// ---------------------------------------------------------------------------
__global__ __launch_bounds__(NTHR, 4)
void mega_kernel(const float* __restrict__ F, const float* __restrict__ Wt,
                 _Float16* __restrict__ OMa, _Float16* __restrict__ OMb,
                 _Float16* __restrict__ Fh, _Float16* __restrict__ Bth) {
  __shared__ __align__(16) _Float16 smem[2 * 128 * BKK];  // 32 KB
  const int bid = blockIdx.x;
  const int t = threadIdx.x;
  cg::grid_group grid = cg::this_grid();

  prep_features(F, Fh, bid * NTHR + t, GSTRIDE);
  prep_weights(Wt, Bth, (float(*)[33])smem, bid, t, NBLK);

  __threadfence();
  grid.sync();

  conv_dispatch(Fh, Bth, OMa, OMb, smem, smem + 128 * BKK, bid, t);
}

__global__ __launch_bounds__(256)
void pool_kernel(const _Float16* __restrict__ Fh, const float* __restrict__ R,
                 const _Float16* __restrict__ OMa, const _Float16* __restrict__ OMb,
                 float* __restrict__ out) {
  pool_item8(Fh, R, OMa, OMb, out, blockIdx.x * 256 + threadIdx.x);
}

// ---------------------------------------------------------------------------
// Non-coop fallback (same device code, separate launches)
// ---------------------------------------------------------------------------
__global__ __launch_bounds__(256)
void prep_kernel_sa(const float* __restrict__ F, const float* __restrict__ Wt,
                    _Float16* __restrict__ Fh, _Float16* __restrict__ Bth) {
  __shared__ float tile[32][33];
  prep_features(F, Fh, blockIdx.x * 256 + threadIdx.x, gridDim.x * 256);
  prep_weights(Wt, Bth, tile, blockIdx.x, threadIdx.x, gridDim.x);
}

__global__ __launch_bounds__(256, 4)
void conv_kernel_sa(const _Float16* __restrict__ Fh, const _Float16* __restrict__ Bth,
                    _Float16* __restrict__ OMa, _Float16* __restrict__ OMb) {
  __shared__ __align__(16) _Float16 smem[2 * 128 * BKK];
  conv_dispatch(Fh, Bth, OMa, OMb, smem, smem + 128 * BKK, blockIdx.x, threadIdx.x);
}

extern "C" void kernel_launch(void* const* d_in, const int* in_sizes, int n_in,
                              void* d_out, int out_size, void* d_ws, size_t ws_size,
                              hipStream_t stream) {
  const float* F  = (const float*)d_in[0];   // features [1,128,128,392] fp32
  const float* R  = (const float*)d_in[1];   // rois [2048,5] fp32
  const float* Wt = (const float*)d_in[2];   // conv_w [3,3,392,392] fp32
  float* out = (float*)d_out;                // [2048,8,7,7] fp32

  const size_t omBytes  = (size_t)NPIX * CC * sizeof(_Float16);            // 12.85 MB
  const size_t fhBytes  = (size_t)HPAD * HPAD * CPAD * sizeof(_Float16);   // 15.14 MB
  // Bth: 416 * 4032 * 2B = 3.35 MB; total ~44.2 MB

  _Float16* OMa = (_Float16*)d_ws;
  _Float16* OMb = OMa + (size_t)NPIX * CC;
  _Float16* Fh  = (_Float16*)((char*)d_ws + 2 * omBytes);
  _Float16* Bth = (_Float16*)((char*)d_ws + 2 * omBytes + fhBytes);

  int maxBlk = 0;
  hipError_t qerr = hipOccupancyMaxActiveBlocksPerMultiprocessor(&maxBlk, mega_kernel, NTHR, 0);
  bool coopOk = (qerr == hipSuccess && maxBlk >= 4);

  if (coopOk) {
    void* args[] = {(void*)&F, (void*)&Wt, (void*)&OMa, (void*)&OMb,
                    (void*)&Fh, (void*)&Bth};
    hipError_t err = hipLaunchCooperativeKernel((const void*)mega_kernel,
                                                dim3(NBLK), dim3(NTHR),
                                                args, 0, stream);
    if (err != hipSuccess) {
      (void)hipGetLastError();
      coopOk = false;
    }
  }
  if (!coopOk) {
    prep_kernel_sa<<<2048, 256, 0, stream>>>(F, Wt, Fh, Bth);
    conv_kernel_sa<<<NBLK, 256, 0, stream>>>(Fh, Bth, OMa, OMb);
  }

  pool_kernel<<<POOL8 / 256, 256, 0, stream>>>(Fh, R, OMa, OMb, out);
}